// Round 8
// baseline (69.154 us; speedup 1.0000x reference)
//
#include <hip/hip_runtime.h>
#include <math.h>

// Problem constants (from reference)
#define N_NODES 8192        // N_IN == N_OUT == 8192
#define C_OUT 32
#define GDIM  192           // 64 cells * 3 input channels
#define NB    16            // nodes per scatter block
constexpr float INV_RADIUS   = 1.0f / 0.1125f;   // RADIUS = 1.5*6*0.025/2
constexpr float EPS          = 1e-12f;
constexpr float FOUR_OVER_PI = 1.27323954473516f;

// Fast hardware transcendentals (no IEEE-div sequence, no ocml calls).
__device__ __forceinline__ float frcp(float x)  { float r; asm("v_rcp_f32 %0, %1"  : "=v"(r) : "v"(x)); return r; }
__device__ __forceinline__ float frsq(float x)  { float r; asm("v_rsq_f32 %0, %1"  : "=v"(r) : "v"(x)); return r; }
__device__ __forceinline__ float fsqrt_(float x){ float r; asm("v_sqrt_f32 %0, %1" : "=v"(r) : "v"(x)); return r; }

// TRUE hardware LDS atomic add. Generic pointers to LDS on gfx9+ are
// {aperture_hi32 | lds_byte_addr}; the low 32 bits are the DS address.
// This bypasses whatever flat/global lowering HIP picks for atomicAdd-
// on-generic-pointer (suspected cause of the 52us invariant).
__device__ __forceinline__ void ds_addf(float* gp, float v) {
    unsigned a = (unsigned)(unsigned long long)gp;
    asm volatile("ds_add_f32 %0, %1" :: "v"(a), "v"(v));
}

__device__ __forceinline__ float sgnf(float v) {
    return (v > 0.f) ? 1.f : ((v < 0.f) ? -1.f : 0.f);
}

// minimax odd polynomial for atan(q), |q| <= 1, max err ~1e-5
__device__ __forceinline__ float atan01(float q) {
    float t = q * q;
    float p = fmaf(t, -0.01172120f, 0.05265332f);
    p = fmaf(t, p, -0.11643287f);
    p = fmaf(t, p,  0.19354346f);
    p = fmaf(t, p, -0.33262347f);
    p = fmaf(t, p,  0.99997726f);
    return q * p;
}

// Workspace layout (d_ws):
//   pv      : 8192 * 8 floats  (pos.xyz,0, vel.xyz,0)   = 262144 B  @ 0
//   row_off : 8193 ints                                  =  32772 B  @ 262144
//   G       : 8192 * 192 floats                          = 6291456 B @ 294928 (16B aligned)
#define PV_OFF   0
#define ROFF_OFF 262144
#define G_OFF    294928

// Kernel 1: CSR row offsets from sorted dst + pack pos0/vel into float4 pairs.
__global__ __launch_bounds__(256) void prep_kernel(
    const float* __restrict__ pos0,
    const float* __restrict__ vel,
    const int*   __restrict__ dst,
    const float* __restrict__ mask,
    int E,
    int*   __restrict__ row_off,
    float* __restrict__ pv)
{
    int n = blockIdx.x * blockDim.x + threadIdx.x;
    if (n < N_NODES) {
        float4 p = make_float4(pos0[3*n+0], pos0[3*n+1], pos0[3*n+2], 0.f);
        float4 v = make_float4(vel [3*n+0], vel [3*n+1], vel [3*n+2], 0.f);
        ((float4*)pv)[2*n+0] = p;
        ((float4*)pv)[2*n+1] = v;
    }
    if (n > N_NODES) return;
    int lo = 0, hi = E;
    while (lo < hi) { int mid = (lo + hi) >> 1; if (mask[mid] != 0.f) lo = mid + 1; else hi = mid; }
    int Ereal = lo;
    if (n == N_NODES) { row_off[n] = Ereal; return; }
    lo = 0; hi = Ereal;
    while (lo < hi) { int mid = (lo + hi) >> 1; if (dst[mid] < n) lo = mid + 1; else hi = mid; }
    row_off[n] = lo;
}

// Kernel 2: EDGE-PARALLEL scatter, identical to round 7 except the LDS
// accumulation uses inline-asm ds_add_f32 (single-variable A/B).
__global__ __launch_bounds__(256) void scatter_kernel(
    const float* __restrict__ pv,
    const float* __restrict__ pos1,
    const int*   __restrict__ src,
    const int*   __restrict__ dst,
    const int*   __restrict__ row_off,
    float* __restrict__ G)
{
    __shared__ float Gl[NB * GDIM];     // 12 KiB
    __shared__ float posl[NB * 4];

    int t = threadIdx.x;
    int n0 = blockIdx.x * NB;

    if (t < NB) {
        posl[t*4+0] = pos1[(n0+t)*3+0];
        posl[t*4+1] = pos1[(n0+t)*3+1];
        posl[t*4+2] = pos1[(n0+t)*3+2];
    }
    #pragma unroll
    for (int i = t; i < NB * GDIM; i += 256) Gl[i] = 0.f;
    __syncthreads();

    int e0 = row_off[n0], e1 = row_off[n0 + NB];
    int rot = t & 7;

    for (int e = e0 + t; e < e1; e += 256) {
        int s = src[e];
        int d = dst[e] - n0;
        float4 p = ((const float4*)pv)[2*s+0];
        float4 v = ((const float4*)pv)[2*s+1];
        float px = posl[d*4+0], py = posl[d*4+1], pz = posl[d*4+2];

        float rx = (p.x - px) * INV_RADIUS;
        float ry = (p.y - py) * INV_RADIUS;
        float rz = (p.z - pz) * INV_RADIUS;
        float r2 = rx*rx + ry*ry + rz*rz;
        if (r2 >= 1.f) continue;
        float om  = 1.f - r2;
        float win = om * om * om;

        // ball -> cube (volume preserving), branchless
        float x = rx, y = ry, z = rz;
        float ax2y2 = x*x + y*y;
        float norm  = fsqrt_(r2 + EPS);
        bool  top   = 1.25f * z * z > ax2y2;
        float s_top  = fsqrt_(3.f * norm * frcp(norm + fabsf(z) + EPS));
        float s_side = norm * frsq(ax2y2 + EPS);
        float sel = top ? s_top : s_side;
        float cx = x * sel;
        float cy = y * sel;
        float cz = top ? sgnf(z) * norm : 1.5f * z;
        bool zero = r2 < 1e-12f;
        cx = zero ? 0.f : cx;  cy = zero ? 0.f : cy;  cz = zero ? 0.f : cz;

        float cx2 = cx*cx, cy2 = cy*cy;
        float nxy = fsqrt_(cx2 + cy2 + EPS);
        bool  c1  = cx2 >= cy2;
        float xs  = (fabsf(cx) > EPS) ? cx : 1.f;
        float ys  = (fabsf(cy) > EPS) ? cy : 1.f;
        float num = c1 ? cy : cx;
        float den = c1 ? xs : ys;
        float at  = atan01(num * frcp(den)) * FOUR_OVER_PI * nxy;
        float scx = sgnf(cx), scy = sgnf(cy);
        float ux = c1 ? scx * nxy : scy * at;
        float uy = c1 ? scx * at  : scy * nxy;
        bool zxy = (cx2 + cy2) < 1e-12f;
        ux = zxy ? 0.f : ux;  uy = zxy ? 0.f : uy;

        // grid coords in [0,3], corner index + fractions
        float gx = fminf(fmaxf((ux + 1.f) * 1.5f, 0.f), 3.f);
        float gy = fminf(fmaxf((uy + 1.f) * 1.5f, 0.f), 3.f);
        float gz = fminf(fmaxf((cz + 1.f) * 1.5f, 0.f), 3.f);
        int ix = min((int)gx, 2);
        int iy = min((int)gy, 2);
        int iz = min((int)gz, 2);
        float fx = gx - (float)ix;
        float fy = gy - (float)iy;
        float fz = gz - (float)iz;

        float ofx = 1.f - fx, ofy = 1.f - fy, ofz = 1.f - fz;
        int base = (iz * 4 + iy) * 4 + ix;
        float* Gd = Gl + d * GDIM;

        // Lane-rotated corner order: colliding lanes hit different addresses
        // on each DS instruction.
        #pragma unroll
        for (int k = 0; k < 8; ++k) {
            int c  = k ^ rot;
            float wz = (c & 4) ? fz : ofz;
            float wy = (c & 2) ? fy : ofy;
            float wx = (c & 1) ? fx : ofx;
            float w  = wz * wy * wx * win;
            int idx  = base + ((c & 4) << 2) + ((c & 2) << 1) + (c & 1);
            int a    = idx * 3;
            ds_addf(&Gd[a + 0], w * v.x);
            ds_addf(&Gd[a + 1], w * v.y);
            ds_addf(&Gd[a + 2], w * v.z);
        }
    }

    // drain our hand-issued DS ops before the barrier (compiler can't see them)
    asm volatile("s_waitcnt lgkmcnt(0)" ::: "memory");
    __syncthreads();

    // coalesced block writeout: Gl is exactly rows n0..n0+15 of G
    const float4* Gs = (const float4*)Gl;
    float4* Gg = (float4*)(G + (size_t)n0 * GDIM);
    #pragma unroll
    for (int i = t; i < NB * GDIM / 4; i += 256) Gg[i] = Gs[i];
}

// Kernel 3: out[n][o] = b[o] + sum_j G[n][j] * W[j][o]; 8 nodes per 256-thr block.
__global__ __launch_bounds__(256) void gemm_kernel(
    const float* __restrict__ G,
    const float* __restrict__ W,
    const float* __restrict__ b,
    float* __restrict__ out)
{
    __shared__ float Wl[GDIM * C_OUT];   // 24 KiB
    __shared__ float Gls[8 * GDIM];      //  6 KiB
    __shared__ float bl[C_OUT];
    int t = threadIdx.x;
    for (int i = t; i < GDIM * C_OUT / 4; i += 256)
        ((float4*)Wl)[i] = ((const float4*)W)[i];
    if (t < C_OUT) bl[t] = b[t];
    const float4* Gg = (const float4*)(G + (size_t)blockIdx.x * 8 * GDIM);
    for (int i = t; i < 8 * GDIM / 4; i += 256)
        ((float4*)Gls)[i] = Gg[i];
    __syncthreads();

    int node = t >> 5, o = t & 31;
    const float* g = Gls + node * GDIM;
    float acc = bl[o];
    #pragma unroll 8
    for (int j = 0; j < GDIM; ++j)
        acc += g[j] * Wl[j * C_OUT + o];
    out[(blockIdx.x * 8 + node) * C_OUT + o] = acc;
}

extern "C" void kernel_launch(void* const* d_in, const int* in_sizes, int n_in,
                              void* d_out, int out_size, void* d_ws, size_t ws_size,
                              hipStream_t stream)
{
    const float* vel  = (const float*)d_in[0];
    const float* pos0 = (const float*)d_in[1];
    const float* pos1 = (const float*)d_in[2];
    const float* W    = (const float*)d_in[3];
    const float* b    = (const float*)d_in[4];
    const int*   src  = (const int*)d_in[5];
    const int*   dst  = (const int*)d_in[6];
    const float* mask = (const float*)d_in[7];
    int E = in_sizes[5];

    char* ws = (char*)d_ws;
    float* pv      = (float*)(ws + PV_OFF);
    int*   row_off = (int*)  (ws + ROFF_OFF);
    float* G       = (float*)(ws + G_OFF);

    prep_kernel<<<(N_NODES + 256) / 256, 256, 0, stream>>>(pos0, vel, dst, mask, E, row_off, pv);
    scatter_kernel<<<N_NODES / NB, 256, 0, stream>>>(pv, pos1, src, dst, row_off, G);
    gemm_kernel<<<N_NODES / 8, 256, 0, stream>>>(G, W, b, (float*)d_out);
}

// Round 9
// 43.625 us; speedup vs baseline: 1.5852x; 1.5852x over previous
//
#include <hip/hip_runtime.h>
#include <math.h>

// Problem constants (from reference)
#define N_NODES 8192        // N_IN == N_OUT == 8192
#define C_OUT 32
#define GDIM  192           // 64 cells * 3 input channels
constexpr float INV_RADIUS   = 1.0f / 0.1125f;   // RADIUS = 1.5*6*0.025/2
constexpr float EPS          = 1e-12f;
constexpr float FOUR_OVER_PI = 1.27323954473516f;

// Fast hardware transcendentals (no IEEE-div sequence, no ocml calls).
__device__ __forceinline__ float frcp(float x)  { float r; asm("v_rcp_f32 %0, %1"  : "=v"(r) : "v"(x)); return r; }
__device__ __forceinline__ float frsq(float x)  { float r; asm("v_rsq_f32 %0, %1"  : "=v"(r) : "v"(x)); return r; }
__device__ __forceinline__ float fsqrt_(float x){ float r; asm("v_sqrt_f32 %0, %1" : "=v"(r) : "v"(x)); return r; }

__device__ __forceinline__ float sgnf(float v) {
    return (v > 0.f) ? 1.f : ((v < 0.f) ? -1.f : 0.f);
}

// broadcast lane r's float to all lanes (r wave-uniform) -> lands in SGPR
__device__ __forceinline__ float rl(float x, int r) {
    return __int_as_float(__builtin_amdgcn_readlane(__float_as_int(x), r));
}

// minimax odd polynomial for atan(q), |q| <= 1, max err ~1e-5
__device__ __forceinline__ float atan01(float q) {
    float t = q * q;
    float p = fmaf(t, -0.01172120f, 0.05265332f);
    p = fmaf(t, p, -0.11643287f);
    p = fmaf(t, p,  0.19354346f);
    p = fmaf(t, p, -0.33262347f);
    p = fmaf(t, p,  0.99997726f);
    return q * p;
}

// Workspace layout (d_ws):
//   pv      : 8192 * 8 floats  (pos.xyz,0, vel.xyz,0)   = 262144 B  @ 0
//   row_off : 8193 ints                                  =  32772 B  @ 262144
//   G       : 8192 * 192 floats                          = 6291456 B @ 294928 (16B aligned)
#define PV_OFF   0
#define ROFF_OFF 262144
#define G_OFF    294928

// Kernel 1: CSR row offsets from sorted dst + pack pos0/vel into float4 pairs.
__global__ __launch_bounds__(256) void prep_kernel(
    const float* __restrict__ pos0,
    const float* __restrict__ vel,
    const int*   __restrict__ dst,
    const float* __restrict__ mask,
    int E,
    int*   __restrict__ row_off,
    float* __restrict__ pv)
{
    int n = blockIdx.x * blockDim.x + threadIdx.x;
    if (n < N_NODES) {
        float4 p = make_float4(pos0[3*n+0], pos0[3*n+1], pos0[3*n+2], 0.f);
        float4 v = make_float4(vel [3*n+0], vel [3*n+1], vel [3*n+2], 0.f);
        ((float4*)pv)[2*n+0] = p;
        ((float4*)pv)[2*n+1] = v;
    }
    if (n > N_NODES) return;
    int lo = 0, hi = E;
    while (lo < hi) { int mid = (lo + hi) >> 1; if (mask[mid] != 0.f) lo = mid + 1; else hi = mid; }
    int Ereal = lo;
    if (n == N_NODES) { row_off[n] = Ereal; return; }
    lo = 0; hi = Ereal;
    while (lo < hi) { int mid = (lo + hi) >> 1; if (dst[mid] < n) lo = mid + 1; else hi = mid; }
    row_off[n] = lo;
}

// Kernel 2: GATHER-FORM cconv. One wave per node; lane L owns cell L (64
// cells == 64 lanes). Phase A: 64 edges processed lane-parallel -> per-lane
// record (gx,gy,gz, win*v) in REGISTERS. Phase B: readlane-broadcast each
// record; every lane FMAs its own hat-function weight into 3 reg accums.
// NO LDS, NO atomics, NO barriers anywhere.
__global__ __launch_bounds__(256) void cconv_kernel(
    const float* __restrict__ pv,
    const float* __restrict__ pos1,
    const int*   __restrict__ src,
    const int*   __restrict__ row_off,
    float* __restrict__ G)
{
    int t = threadIdx.x, wave = t >> 6, lane = t & 63;
    int n = blockIdx.x * 4 + wave;

    // own cell coordinates (cell = iz*16 + iy*4 + ix = lane)
    float jx = (float)(lane & 3);
    float jy = (float)((lane >> 2) & 3);
    float jz = (float)(lane >> 4);

    float ax = 0.f, ay = 0.f, az = 0.f;     // G[n][3*lane + 0..2]

    float px = pos1[3*n+0], py = pos1[3*n+1], pz = pos1[3*n+2];
    int e0 = row_off[n], e1 = row_off[n+1];

    for (int eb = e0; eb < e1; eb += 64) {
        int cnt = min(64, e1 - eb);         // wave-uniform
        int e = eb + lane;
        bool valid = lane < cnt;
        int s = src[valid ? e : eb];
        float4 p = ((const float4*)pv)[2*s+0];
        float4 v = ((const float4*)pv)[2*s+1];

        // ---- Phase A: per-edge geometry (lane-parallel) ----
        float rx = (p.x - px) * INV_RADIUS;
        float ry = (p.y - py) * INV_RADIUS;
        float rz = (p.z - pz) * INV_RADIUS;
        float r2 = rx*rx + ry*ry + rz*rz;
        float om  = 1.f - r2;
        float win = om * om * om;
        if (!valid || r2 >= 1.f) win = 0.f;

        float x = rx, y = ry, z = rz;
        float ax2y2 = x*x + y*y;
        float norm  = fsqrt_(r2 + EPS);
        bool  top   = 1.25f * z * z > ax2y2;
        float s_top  = fsqrt_(3.f * norm * frcp(norm + fabsf(z) + EPS));
        float s_side = norm * frsq(ax2y2 + EPS);
        float sel = top ? s_top : s_side;
        float cx = x * sel;
        float cy = y * sel;
        float cz = top ? sgnf(z) * norm : 1.5f * z;
        bool zero = r2 < 1e-12f;
        cx = zero ? 0.f : cx;  cy = zero ? 0.f : cy;  cz = zero ? 0.f : cz;

        float cx2 = cx*cx, cy2 = cy*cy;
        float nxy = fsqrt_(cx2 + cy2 + EPS);
        bool  c1  = cx2 >= cy2;
        float xs  = (fabsf(cx) > EPS) ? cx : 1.f;
        float ys  = (fabsf(cy) > EPS) ? cy : 1.f;
        float num = c1 ? cy : cx;
        float den = c1 ? xs : ys;
        float at  = atan01(num * frcp(den)) * FOUR_OVER_PI * nxy;
        float scx = sgnf(cx), scy = sgnf(cy);
        float ux = c1 ? scx * nxy : scy * at;
        float uy = c1 ? scx * at  : scy * nxy;
        bool zxy = (cx2 + cy2) < 1e-12f;
        ux = zxy ? 0.f : ux;  uy = zxy ? 0.f : uy;

        // grid coords in [0,3]; hat function replaces floor/frac/corners
        float gx = fminf(fmaxf((ux + 1.f) * 1.5f, 0.f), 3.f);
        float gy = fminf(fmaxf((uy + 1.f) * 1.5f, 0.f), 3.f);
        float gz = fminf(fmaxf((cz + 1.f) * 1.5f, 0.f), 3.f);

        float wvx = win * v.x, wvy = win * v.y, wvz = win * v.z;

        // ---- Phase B: broadcast-reduce all cnt records (uniform loop) ----
        #pragma unroll 2
        for (int r = 0; r < cnt; ++r) {
            float sgx = rl(gx, r),  sgy = rl(gy, r),  sgz = rl(gz, r);
            float svx = rl(wvx, r), svy = rl(wvy, r), svz = rl(wvz, r);
            float wxc = fmaxf(1.f - fabsf(sgx - jx), 0.f);
            float wyc = fmaxf(1.f - fabsf(sgy - jy), 0.f);
            float wzc = fmaxf(1.f - fabsf(sgz - jz), 0.f);
            float w = wxc * wyc * wzc;
            ax = fmaf(w, svx, ax);
            ay = fmaf(w, svy, ay);
            az = fmaf(w, svz, az);
        }
    }

    // lane L writes its cell's 3 channels: contiguous 12B per lane
    float* Gn = G + (size_t)n * GDIM + lane * 3;
    Gn[0] = ax; Gn[1] = ay; Gn[2] = az;
}

// Kernel 3: out[n][o] = b[o] + sum_j G[n][j] * W[j][o]; 32 nodes per block
// (W staged once per 32 nodes -> 8x less W re-staging than before).
__global__ __launch_bounds__(256) void gemm_kernel(
    const float* __restrict__ G,
    const float* __restrict__ W,
    const float* __restrict__ b,
    float* __restrict__ out)
{
    __shared__ float Wl[GDIM * C_OUT];    // 24 KiB
    __shared__ float Gls[32 * GDIM];      // 24 KiB
    int t = threadIdx.x;
    #pragma unroll
    for (int i = t; i < GDIM * C_OUT / 4; i += 256)
        ((float4*)Wl)[i] = ((const float4*)W)[i];
    const float4* Gg = (const float4*)(G + (size_t)blockIdx.x * 32 * GDIM);
    #pragma unroll
    for (int i = t; i < 32 * GDIM / 4; i += 256)
        ((float4*)Gls)[i] = Gg[i];
    __syncthreads();

    int o = t & 31, nl = t >> 5;          // nl in 0..7
    float bo = b[o];
    #pragma unroll
    for (int k = 0; k < 4; ++k) {
        int node = nl + k * 8;
        const float* g = Gls + node * GDIM;
        float acc = bo;
        #pragma unroll 8
        for (int j = 0; j < GDIM; ++j)
            acc = fmaf(g[j], Wl[j * C_OUT + o], acc);
        out[(blockIdx.x * 32 + node) * C_OUT + o] = acc;
    }
}

extern "C" void kernel_launch(void* const* d_in, const int* in_sizes, int n_in,
                              void* d_out, int out_size, void* d_ws, size_t ws_size,
                              hipStream_t stream)
{
    const float* vel  = (const float*)d_in[0];
    const float* pos0 = (const float*)d_in[1];
    const float* pos1 = (const float*)d_in[2];
    const float* W    = (const float*)d_in[3];
    const float* b    = (const float*)d_in[4];
    const int*   src  = (const int*)d_in[5];
    const int*   dst  = (const int*)d_in[6];
    const float* mask = (const float*)d_in[7];
    int E = in_sizes[5];

    char* ws = (char*)d_ws;
    float* pv      = (float*)(ws + PV_OFF);
    int*   row_off = (int*)  (ws + ROFF_OFF);
    float* G       = (float*)(ws + G_OFF);

    prep_kernel<<<(N_NODES + 256) / 256, 256, 0, stream>>>(pos0, vel, dst, mask, E, row_off, pv);
    cconv_kernel<<<N_NODES / 4, 256, 0, stream>>>(pv, pos1, src, row_off, G);
    gemm_kernel<<<N_NODES / 32, 256, 0, stream>>>(G, W, b, (float*)d_out);
}

// Round 10
// 27.012 us; speedup vs baseline: 2.5601x; 1.6150x over previous
//
#include <hip/hip_runtime.h>
#include <math.h>

// Problem constants (from reference)
#define N_NODES 8192        // N_IN == N_OUT == 8192
#define C_OUT 32
#define GD    192           // 12 used cols * 16 rows of the 16x16 MFMA tile
constexpr float INV_RADIUS   = 1.0f / 0.1125f;   // RADIUS = 1.5*6*0.025/2
constexpr float EPS          = 1e-12f;
constexpr float FOUR_OVER_PI = 1.27323954473516f;

typedef __attribute__((ext_vector_type(8))) _Float16 half8;
typedef __attribute__((ext_vector_type(4))) float    floatx4;

// Fast hardware transcendentals (no IEEE-div sequence, no ocml calls).
__device__ __forceinline__ float frcp(float x)  { float r; asm("v_rcp_f32 %0, %1"  : "=v"(r) : "v"(x)); return r; }
__device__ __forceinline__ float frsq(float x)  { float r; asm("v_rsq_f32 %0, %1"  : "=v"(r) : "v"(x)); return r; }
__device__ __forceinline__ float fsqrt_(float x){ float r; asm("v_sqrt_f32 %0, %1" : "=v"(r) : "v"(x)); return r; }

__device__ __forceinline__ float sgnf(float v) {
    return (v > 0.f) ? 1.f : ((v < 0.f) ? -1.f : 0.f);
}

// pack two f32 -> one u32 of two f16
__device__ __forceinline__ unsigned pkh(float a, float b) {
    union { _Float16 h[2]; unsigned u; } x;
    x.h[0] = (_Float16)a; x.h[1] = (_Float16)b;
    return x.u;
}

// minimax odd polynomial for atan(q), |q| <= 1, max err ~1e-5
__device__ __forceinline__ float atan01(float q) {
    float t = q * q;
    float p = fmaf(t, -0.01172120f, 0.05265332f);
    p = fmaf(t, p, -0.11643287f);
    p = fmaf(t, p,  0.19354346f);
    p = fmaf(t, p, -0.33262347f);
    p = fmaf(t, p,  0.99997726f);
    return q * p;
}

// Workspace layout (d_ws):
//   pv   : 8192*8 floats                       = 262144 B @ 0
//   roff : 8193 ints                           =  32772 B @ 262144
//   W2   : 192*32 floats (reordered weights)   =  24576 B @ 294928
//   G2   : 8192*192 floats (n*16+m layout)     = 6291456 B @ 319520
#define PV_OFF   0
#define ROFF_OFF 262144
#define W2_OFF   294928
#define G2_OFF   319520

// Kernel 1: CSR row offsets + pv packing + W reorder.
// W2[(n*16+m)*32+o] = W[cell][c][o] with m=(iz,iy), n=ix*3+c.
__global__ __launch_bounds__(256) void prep_kernel(
    const float* __restrict__ pos0,
    const float* __restrict__ vel,
    const float* __restrict__ W,
    const int*   __restrict__ dst,
    const float* __restrict__ mask,
    int E,
    int*   __restrict__ row_off,
    float* __restrict__ pv,
    float* __restrict__ W2)
{
    int n = blockIdx.x * blockDim.x + threadIdx.x;
    if (n < GD * C_OUT / 32 * 32 && n < 6144) {
        int o = n & 31, j = n >> 5;          // j = n_col*16 + m_row
        int nc = j >> 4, m = j & 15;
        int iz = m >> 2, iy = m & 3, ix = nc / 3, c = nc % 3;
        int cell = (iz * 4 + iy) * 4 + ix;
        W2[j * 32 + o] = W[(cell * 3 + c) * 32 + o];
    }
    if (n < N_NODES) {
        float4 p = make_float4(pos0[3*n+0], pos0[3*n+1], pos0[3*n+2], 0.f);
        float4 v = make_float4(vel [3*n+0], vel [3*n+1], vel [3*n+2], 0.f);
        ((float4*)pv)[2*n+0] = p;
        ((float4*)pv)[2*n+1] = v;
    }
    if (n > N_NODES) return;
    int lo = 0, hi = E;
    while (lo < hi) { int mid = (lo + hi) >> 1; if (mask[mid] != 0.f) lo = mid + 1; else hi = mid; }
    int Ereal = lo;
    if (n == N_NODES) { row_off[n] = Ereal; return; }
    lo = 0; hi = Ereal;
    while (lo < hi) { int mid = (lo + hi) >> 1; if (dst[mid] < n) lo = mid + 1; else hi = mid; }
    row_off[n] = lo;
}

// Kernel 2: MFMA cconv. One wave per node. Per 64-edge batch:
//  Phase A (lane-parallel): geometry -> separable hat factors ->
//    A[m]=hz*hy (16 f16), B[n]=hx*win*v[c] (12 f16) staged in wave-private LDS
//    (72 B/record stride).
//  Phase MFMA: 2x mfma_f32_16x16x32_f16 accumulate G[16x16] over 64 records.
// Invalid/padded records have B==0 -> contribute nothing (A garbage is finite).
__global__ __launch_bounds__(256) void cconv_kernel(
    const float* __restrict__ pv,
    const float* __restrict__ pos1,
    const int*   __restrict__ src,
    const int*   __restrict__ row_off,
    float* __restrict__ G2)
{
    __shared__ float Glds[4][64 * 18];   // 4 waves x 64 records x 72B = 18 KiB

    int t = threadIdx.x, wave = t >> 6, lane = t & 63;
    int q = lane >> 4, mr = lane & 15;
    int node = blockIdx.x * 4 + wave;

    floatx4 acc = {0.f, 0.f, 0.f, 0.f};

    float px = pos1[3*node+0], py = pos1[3*node+1], pz = pos1[3*node+2];
    int e0 = row_off[node], e1 = row_off[node+1];

    float* myrec = &Glds[wave][lane * 18];
    const _Float16* hp = (const _Float16*)&Glds[wave][0];

    for (int eb = e0; eb < e1; eb += 64) {
        int cnt = min(64, e1 - eb);          // wave-uniform
        bool valid = lane < cnt;
        int s = src[valid ? eb + lane : eb];
        float4 p = ((const float4*)pv)[2*s+0];
        float4 v = ((const float4*)pv)[2*s+1];

        // ---- Phase A: geometry (lane-parallel) ----
        float rx = (p.x - px) * INV_RADIUS;
        float ry = (p.y - py) * INV_RADIUS;
        float rz = (p.z - pz) * INV_RADIUS;
        float r2 = rx*rx + ry*ry + rz*rz;
        float om  = 1.f - r2;
        float win = om * om * om;
        if (!valid || r2 >= 1.f) win = 0.f;

        float x = rx, y = ry, z = rz;
        float ax2y2 = x*x + y*y;
        float norm  = fsqrt_(r2 + EPS);
        bool  top   = 1.25f * z * z > ax2y2;
        float s_top  = fsqrt_(3.f * norm * frcp(norm + fabsf(z) + EPS));
        float s_side = norm * frsq(ax2y2 + EPS);
        float sel = top ? s_top : s_side;
        float cx = x * sel;
        float cy = y * sel;
        float cz = top ? sgnf(z) * norm : 1.5f * z;
        bool zero = r2 < 1e-12f;
        cx = zero ? 0.f : cx;  cy = zero ? 0.f : cy;  cz = zero ? 0.f : cz;

        float cx2 = cx*cx, cy2 = cy*cy;
        float nxy = fsqrt_(cx2 + cy2 + EPS);
        bool  c1  = cx2 >= cy2;
        float xs  = (fabsf(cx) > EPS) ? cx : 1.f;
        float ys  = (fabsf(cy) > EPS) ? cy : 1.f;
        float num = c1 ? cy : cx;
        float den = c1 ? xs : ys;
        float at  = atan01(num * frcp(den)) * FOUR_OVER_PI * nxy;
        float scx = sgnf(cx), scy = sgnf(cy);
        float ux = c1 ? scx * nxy : scy * at;
        float uy = c1 ? scx * at  : scy * nxy;
        bool zxy = (cx2 + cy2) < 1e-12f;
        ux = zxy ? 0.f : ux;  uy = zxy ? 0.f : uy;

        float gx = fminf(fmaxf((ux + 1.f) * 1.5f, 0.f), 3.f);
        float gy = fminf(fmaxf((uy + 1.f) * 1.5f, 0.f), 3.f);
        float gz = fminf(fmaxf((cz + 1.f) * 1.5f, 0.f), 3.f);

        float wvx = win * v.x, wvy = win * v.y, wvz = win * v.z;

        // separable hat factors (exactly reproduce trilinear corner weights)
        float hx0 = fmaxf(1.f - fabsf(gx - 0.f), 0.f);
        float hx1 = fmaxf(1.f - fabsf(gx - 1.f), 0.f);
        float hx2 = fmaxf(1.f - fabsf(gx - 2.f), 0.f);
        float hx3 = fmaxf(1.f - fabsf(gx - 3.f), 0.f);
        float hy0 = fmaxf(1.f - fabsf(gy - 0.f), 0.f);
        float hy1 = fmaxf(1.f - fabsf(gy - 1.f), 0.f);
        float hy2 = fmaxf(1.f - fabsf(gy - 2.f), 0.f);
        float hy3 = fmaxf(1.f - fabsf(gy - 3.f), 0.f);
        float hz0 = fmaxf(1.f - fabsf(gz - 0.f), 0.f);
        float hz1 = fmaxf(1.f - fabsf(gz - 1.f), 0.f);
        float hz2 = fmaxf(1.f - fabsf(gz - 2.f), 0.f);
        float hz3 = fmaxf(1.f - fabsf(gz - 3.f), 0.f);

        // A[m] = hz[m>>2]*hy[m&3]  (16 halfs), B[n] = hx[n/3]*wv[n%3] (12 halfs)
        unsigned A0 = pkh(hz0*hy0, hz0*hy1), A1 = pkh(hz0*hy2, hz0*hy3);
        unsigned A2 = pkh(hz1*hy0, hz1*hy1), A3 = pkh(hz1*hy2, hz1*hy3);
        unsigned A4 = pkh(hz2*hy0, hz2*hy1), A5 = pkh(hz2*hy2, hz2*hy3);
        unsigned A6 = pkh(hz3*hy0, hz3*hy1), A7 = pkh(hz3*hy2, hz3*hy3);
        unsigned B0 = pkh(hx0*wvx, hx0*wvy), B1 = pkh(hx0*wvz, hx1*wvx);
        unsigned B2 = pkh(hx1*wvy, hx1*wvz), B3 = pkh(hx2*wvx, hx2*wvy);
        unsigned B4 = pkh(hx2*wvz, hx3*wvx), B5 = pkh(hx3*wvy, hx3*wvz);

        float2* wp = (float2*)myrec;
        wp[0] = make_float2(__uint_as_float(A0), __uint_as_float(A1));
        wp[1] = make_float2(__uint_as_float(A2), __uint_as_float(A3));
        wp[2] = make_float2(__uint_as_float(A4), __uint_as_float(A5));
        wp[3] = make_float2(__uint_as_float(A6), __uint_as_float(A7));
        wp[4] = make_float2(__uint_as_float(B0), __uint_as_float(B1));
        wp[5] = make_float2(__uint_as_float(B2), __uint_as_float(B3));
        wp[6] = make_float2(__uint_as_float(B4), __uint_as_float(B5));
        wp[7] = make_float2(0.f, 0.f);       // zero pad (B cols 12..15)
        __builtin_amdgcn_sched_barrier(0);

        // ---- Phase MFMA: K=32 records per call ----
        int nkk = (cnt > 32) ? 2 : 1;
        for (int kk = 0; kk < nkk; ++kk) {
            union { _Float16 h[8]; half8 v8; } fa, fb;
            #pragma unroll
            for (int i = 0; i < 8; ++i) {
                int rec = kk * 32 + q * 8 + i;   // k-slot relabeling-invariant
                fa.h[i] = hp[rec * 36 + mr];          // A[m=mr] of record
                fb.h[i] = hp[rec * 36 + 16 + mr];     // B[n=mr] of record
            }
            acc = __builtin_amdgcn_mfma_f32_16x16x32_f16(fa.v8, fb.v8, acc, 0, 0, 0);
        }
        __builtin_amdgcn_sched_barrier(0);
    }

    // D layout (verified): col = lane&15, row = 4*(lane>>4)+reg.
    // Store G2[node][n*16 + m] for n<12: one coalesced float4 per lane.
    if (mr < 12) {
        float4* gp = (float4*)(G2 + (size_t)node * GD + mr * 16 + q * 4);
        *gp = make_float4(acc[0], acc[1], acc[2], acc[3]);
    }
}

// Kernel 3: out[n][o] = b[o] + sum_j G2[n][j] * W2[j][o]; 8 nodes/block.
__global__ __launch_bounds__(256) void gemm_kernel(
    const float* __restrict__ G2,
    const float* __restrict__ W2,
    const float* __restrict__ b,
    float* __restrict__ out)
{
    __shared__ float Wl[GD * C_OUT];   // 24 KiB
    __shared__ float Gls[8 * GD];      //  6 KiB
    int t = threadIdx.x;
    #pragma unroll
    for (int i = t; i < GD * C_OUT / 4; i += 256)
        ((float4*)Wl)[i] = ((const float4*)W2)[i];
    const float4* Gg = (const float4*)(G2 + (size_t)blockIdx.x * 8 * GD);
    for (int i = t; i < 8 * GD / 4; i += 256)
        ((float4*)Gls)[i] = Gg[i];
    __syncthreads();

    int o = t & 31, nl = t >> 5;
    const float* g = Gls + nl * GD;
    float acc = b[o];
    #pragma unroll 8
    for (int j = 0; j < GD; ++j)
        acc = fmaf(g[j], Wl[j * C_OUT + o], acc);
    out[(blockIdx.x * 8 + nl) * C_OUT + o] = acc;
}

extern "C" void kernel_launch(void* const* d_in, const int* in_sizes, int n_in,
                              void* d_out, int out_size, void* d_ws, size_t ws_size,
                              hipStream_t stream)
{
    const float* vel  = (const float*)d_in[0];
    const float* pos0 = (const float*)d_in[1];
    const float* pos1 = (const float*)d_in[2];
    const float* W    = (const float*)d_in[3];
    const float* b    = (const float*)d_in[4];
    const int*   src  = (const int*)d_in[5];
    const int*   dst  = (const int*)d_in[6];
    const float* mask = (const float*)d_in[7];
    int E = in_sizes[5];

    char* ws = (char*)d_ws;
    float* pv      = (float*)(ws + PV_OFF);
    int*   row_off = (int*)  (ws + ROFF_OFF);
    float* W2      = (float*)(ws + W2_OFF);
    float* G2      = (float*)(ws + G2_OFF);

    prep_kernel<<<(N_NODES + 256) / 256, 256, 0, stream>>>(pos0, vel, W, dst, mask, E, row_off, pv, W2);
    cconv_kernel<<<N_NODES / 4, 256, 0, stream>>>(pv, pos1, src, row_off, G2);
    gemm_kernel<<<N_NODES / 8, 256, 0, stream>>>(G2, W2, b, (float*)d_out);
}